// Round 8
// baseline (342.830 us; speedup 1.0000x reference)
//
#include <hip/hip_runtime.h>

#define B_ 16
#define C_ 1024
#define D_ 1024
#define H_ 64
#define M_ (B_*C_)   // 16384

typedef __attribute__((ext_vector_type(8))) short bf16x8;
typedef __attribute__((ext_vector_type(8))) unsigned short ushortx8;
typedef __attribute__((ext_vector_type(4))) float f32x4;

__device__ __forceinline__ float wave_max(float v){
  #pragma unroll
  for (int o = 32; o > 0; o >>= 1) v = fmaxf(v, __shfl_xor(v, o));
  return v;
}
__device__ __forceinline__ float wave_sum(float v){
  #pragma unroll
  for (int o = 32; o > 0; o >>= 1) v += __shfl_xor(v, o);
  return v;
}

// fp32 -> bf16 (RNE)
__device__ __forceinline__ ushort f2bf(float f){
  union { float f; unsigned u; } a; a.f = f;
  unsigned r = a.u + 0x7fff + ((a.u >> 16) & 1);
  return (ushort)(r >> 16);
}
__device__ __forceinline__ float bf2f(ushort h){
  union { unsigned u; float f; } a; a.u = ((unsigned)h) << 16; return a.f;
}

// async global->LDS, 16 B per lane; LDS dest is wave-uniform base + lane*16.
__device__ __forceinline__ void lds_cp16(const ushort* g, ushort* l){
  __builtin_amdgcn_global_load_lds(
      (const __attribute__((address_space(1))) void*)g,
      (__attribute__((address_space(3))) void*)l, 16, 0, 0);
}

// ---------------- merged prep: cvt(x) + weight transposes + zero(out) -----
__global__ __launch_bounds__(256) void prep_kernel(
    const float* __restrict__ x, const float* __restrict__ Wf,
    const float* __restrict__ Wg, const float* __restrict__ Wx,
    const float* __restrict__ W1,
    ushort* __restrict__ x_bf, ushort* __restrict__ wt,
    ushort* __restrict__ w1t, float* __restrict__ out)
{
  __shared__ float tile[32][33];
  const int blk = blockIdx.x;
  const int t = threadIdx.x;
  if (blk < 16384) {                       // cvt: x -> bf16, 4 elems/thread
    const int i = blk*256 + t;
    float4 v = ((const float4*)x)[i];
    ushort4 o;
    o.x = f2bf(v.x); o.y = f2bf(v.y); o.z = f2bf(v.z); o.w = f2bf(v.w);
    ((ushort4*)x_bf)[i] = o;
  } else if (blk < 16384 + 3072) {         // tconv of Wf/Wg/Wx -> wt[z]
    const int bb = blk - 16384;
    const int z = bb >> 10, rem = bb & 1023;
    const int n0 = (rem & 31)*32, k0 = (rem >> 5)*32;
    const float* W = (z == 0) ? Wf : (z == 1) ? Wg : Wx;
    ushort* Out = wt + (size_t)z*D_*D_;
    const int tx = t & 31, ty = t >> 5;
    #pragma unroll
    for (int i = 0; i < 32; i += 8)
      tile[ty+i][tx] = W[(size_t)(k0+ty+i)*D_ + n0+tx];
    __syncthreads();
    #pragma unroll
    for (int i = 0; i < 32; i += 8)
      Out[(size_t)(n0+ty+i)*D_ + k0+tx] = f2bf(tile[tx][ty+i]);
  } else if (blk < 16384 + 3072 + 64) {    // tconv of W1 (1024x64) -> w1t
    const int bb = blk - 16384 - 3072;
    const int n0 = (bb & 1)*32, k0 = (bb >> 1)*32;
    const int tx = t & 31, ty = t >> 5;
    #pragma unroll
    for (int i = 0; i < 32; i += 8)
      tile[ty+i][tx] = W1[(size_t)(k0+ty+i)*H_ + n0+tx];
    __syncthreads();
    #pragma unroll
    for (int i = 0; i < 32; i += 8)
      w1t[(size_t)(n0+ty+i)*D_ + k0+tx] = f2bf(tile[tx][ty+i]);
  } else {                                 // zero out[B_*D_] for atomic final
    const int bb = blk - 16384 - 3072 - 64;   // 0..15
    float4 z4 = {0,0,0,0};
    ((float4*)out)[bb*256 + t] = z4;
  }
}

// ---------------- merged QKV projection: NT GEMM, N=3072, BK=64 -----------
// XCD-swizzled: each XCD owns 16 consecutive A-panels (4 MB, L2-resident);
// per panel all 24 n-tiles run consecutively on that XCD.
__global__ __launch_bounds__(256, 3) void proj_kernel(
    const ushort* __restrict__ A, const ushort* __restrict__ Wt,
    const float* __restrict__ bf, const float* __restrict__ bg,
    const float* __restrict__ bx,
    ushort* __restrict__ q, ushort* __restrict__ k, ushort* __restrict__ v)
{
  __shared__ ushort As[128*64];
  __shared__ ushort Bs[128*64];
  const int t = threadIdx.x;
  const int wid = t >> 6, lane = t & 63;

  // block swizzle: id (x-fastest) -> (n-tile x, m-panel p) with p%8 == id%8
  const int id = blockIdx.y * gridDim.x + blockIdx.x;   // 0..3071
  const int xcd = id & 7;
  const int qq = id >> 3;             // 0..383
  const int xk = qq % 24;             // n-tile
  const int p  = (qq / 24) * 8 + xcd; // m-panel 0..127
  const int m0 = p * 128, n0 = xk * 128;
  const int seg = n0 >> 10;                                  // 0:q 1:k 2:v
  const int nloc0 = n0 - (seg << 10);

  const int srow = t >> 3;
  const int sch = ((t & 7) ^ (srow & 7)) * 8;
  const ushort* gaBase = A  + (size_t)(m0 + srow)*1024 + sch;
  const ushort* gbBase = Wt + (size_t)(n0 + srow)*1024 + sch;

  const int quad = lane >> 4, l16 = lane & 15;
  const int wm = wid >> 1, wn = wid & 1;
  const int cx0 = ((0*4 + quad) ^ (l16 & 7)) * 8;
  const int cx1 = ((1*4 + quad) ^ (l16 & 7)) * 8;
  const int arow0 = (wm*64 + l16)*64;
  const int brow0 = (wn*64 + l16)*64;

  f32x4 acc[4][4] = {};

  for (int k0 = 0; k0 < 1024; k0 += 64) {
    #pragma unroll
    for (int i = 0; i < 4; ++i) {
      lds_cp16(gaBase + (size_t)(i*32)*1024, As + (8*wid + 32*i)*64);
      lds_cp16(gbBase + (size_t)(i*32)*1024, Bs + (8*wid + 32*i)*64);
    }
    gaBase += 64; gbBase += 64;
    __syncthreads();
    #pragma unroll
    for (int h = 0; h < 2; ++h) {
      const int cx = h ? cx1 : cx0;
      bf16x8 af[4], bfr[4];
      #pragma unroll
      for (int i = 0; i < 4; ++i) {
        af[i]  = *(const bf16x8*)&As[arow0 + i*1024 + cx];
        bfr[i] = *(const bf16x8*)&Bs[brow0 + i*1024 + cx];
      }
      #pragma unroll
      for (int mt = 0; mt < 4; ++mt)
        #pragma unroll
        for (int nt = 0; nt < 4; ++nt)
          acc[mt][nt] = __builtin_amdgcn_mfma_f32_16x16x32_bf16(
              af[mt], bfr[nt], acc[mt][nt], 0, 0, 0);
    }
    __syncthreads();
  }

  const float* bp = (seg == 0) ? bf : (seg == 1) ? bg : bx;
  ushort* op      = (seg == 0) ? q  : (seg == 1) ? k  : v;
  const int gm_base = m0 + wm*64 + quad*4;
  const int gn_base = nloc0 + wn*64 + l16;
  float bv[4];
  #pragma unroll
  for (int nt = 0; nt < 4; ++nt) bv[nt] = bp[gn_base + nt*16];
  #pragma unroll
  for (int mt = 0; mt < 4; ++mt)
    #pragma unroll
    for (int rr = 0; rr < 4; ++rr) {
      const size_t rowoff = (size_t)(gm_base + mt*16 + rr) * 1024;
      #pragma unroll
      for (int nt = 0; nt < 4; ++nt)
        op[rowoff + gn_base + nt*16] =
            f2bf(fmaxf(acc[mt][nt][rr] + bv[nt], 0.f));
    }
}

// ---------------- energy: NT GEMM, bf16 out, BK=64, XCD-swizzled ----------
__global__ __launch_bounds__(256, 3) void energy_kernel(
    const ushort* __restrict__ Km, const ushort* __restrict__ Qm,
    ushort* __restrict__ E)
{
  __shared__ ushort As[128*64];
  __shared__ ushort Bs[128*64];
  const int t = threadIdx.x;
  const int wid = t >> 6, lane = t & 63;

  // flatten (x=8, y=8, z=16), x fastest; K-panel = (z,y), 128 panels
  const int id = (blockIdx.z * 8 + blockIdx.y) * 8 + blockIdx.x;  // 0..1023
  const int xcd = id & 7;
  const int qq = id >> 3;             // 0..127
  const int xk = qq % 8;              // n-tile (q)
  const int p  = (qq / 8) * 8 + xcd;  // K-panel 0..127
  const int bz = p >> 3, ym = p & 7;
  const int m0 = ym * 128, n0 = xk * 128;
  const ushort* Ab = Km + (size_t)bz * C_ * D_;
  const ushort* Bb = Qm + (size_t)bz * C_ * D_;

  const int srow = t >> 3;
  const int sch = ((t & 7) ^ (srow & 7)) * 8;
  const ushort* gaBase = Ab + (size_t)(m0 + srow)*1024 + sch;
  const ushort* gbBase = Bb + (size_t)(n0 + srow)*1024 + sch;

  const int quad = lane >> 4, l16 = lane & 15;
  const int wm = wid >> 1, wn = wid & 1;
  const int cx0 = ((0*4 + quad) ^ (l16 & 7)) * 8;
  const int cx1 = ((1*4 + quad) ^ (l16 & 7)) * 8;
  const int arow0 = (wm*64 + l16)*64;
  const int brow0 = (wn*64 + l16)*64;

  f32x4 acc[4][4] = {};

  for (int k0 = 0; k0 < 1024; k0 += 64) {
    #pragma unroll
    for (int i = 0; i < 4; ++i) {
      lds_cp16(gaBase + (size_t)(i*32)*1024, As + (8*wid + 32*i)*64);
      lds_cp16(gbBase + (size_t)(i*32)*1024, Bs + (8*wid + 32*i)*64);
    }
    gaBase += 64; gbBase += 64;
    __syncthreads();
    #pragma unroll
    for (int h = 0; h < 2; ++h) {
      const int cx = h ? cx1 : cx0;
      bf16x8 af[4], bfr[4];
      #pragma unroll
      for (int i = 0; i < 4; ++i) {
        af[i]  = *(const bf16x8*)&As[arow0 + i*1024 + cx];
        bfr[i] = *(const bf16x8*)&Bs[brow0 + i*1024 + cx];
      }
      #pragma unroll
      for (int mt = 0; mt < 4; ++mt)
        #pragma unroll
        for (int nt = 0; nt < 4; ++nt)
          acc[mt][nt] = __builtin_amdgcn_mfma_f32_16x16x32_bf16(
              af[mt], bfr[nt], acc[mt][nt], 0, 0, 0);
    }
    __syncthreads();
  }

  ushort* O = E + (size_t)bz * C_ * C_;
  const int gm_base = m0 + wm*64 + quad*4;
  const int gn_base = n0 + wn*64 + l16;
  #pragma unroll
  for (int mt = 0; mt < 4; ++mt)
    #pragma unroll
    for (int rr = 0; rr < 4; ++rr) {
      const size_t rowoff = (size_t)(gm_base + mt*16 + rr) * 1024;
      #pragma unroll
      for (int nt = 0; nt < 4; ++nt)
        O[rowoff + gn_base + nt*16] = f2bf(acc[mt][nt][rr]);
    }
}

// ---------------- pooling MLP via MFMA (BK=32) ----------------------------
__device__ __forceinline__ int fsw(int row){
  return (row & 3) ^ ((row >> 2) & 3);
}
__global__ __launch_bounds__(256) void pool_mfma_kernel(
    const ushort* __restrict__ A, const ushort* __restrict__ Bt,
    const float* __restrict__ b1, const float* __restrict__ W2,
    float* __restrict__ e2out)
{
  __shared__ ushort As[128*32];
  __shared__ ushort Bs[64*32];
  const int t = threadIdx.x;
  const int wid = t >> 6, lane = t & 63;
  const int m0 = blockIdx.x * 128;

  const int r = t >> 2;
  const int kc = ((t & 3) ^ fsw(r)) * 8;
  const ushort* ga0 = A + (size_t)(m0 + r)*1024 + kc;
  const ushort* ga1 = ga0 + (size_t)64*1024;
  const ushort* gb0 = Bt + (size_t)r*1024 + kc;
  ushort* lA = As + wid*512;
  ushort* lB = Bs + wid*512;

  const int quad = lane >> 4, l16 = lane & 15;
  const int fr = fsw(l16);
  const int am0 = (wid*32 + l16)*32 + ((quad ^ fr)*8);
  const int bn0 = l16*32 + ((quad ^ fr)*8);

  f32x4 acc[2][4] = {};

  for (int k0 = 0; k0 < 1024; k0 += 32) {
    lds_cp16(ga0, lA); lds_cp16(ga1, lA + 2048);
    lds_cp16(gb0, lB);
    ga0 += 32; ga1 += 32; gb0 += 32;
    __syncthreads();
    bf16x8 af[2], bfr[4];
    #pragma unroll
    for (int i = 0; i < 2; ++i) af[i] = *(const bf16x8*)&As[am0 + i*512];
    #pragma unroll
    for (int i = 0; i < 4; ++i) bfr[i] = *(const bf16x8*)&Bs[bn0 + i*512];
    #pragma unroll
    for (int mt = 0; mt < 2; ++mt)
      #pragma unroll
      for (int nt = 0; nt < 4; ++nt)
        acc[mt][nt] = __builtin_amdgcn_mfma_f32_16x16x32_bf16(
            af[mt], bfr[nt], acc[mt][nt], 0, 0, 0);
    __syncthreads();
  }

  float b1v[4], w2v[4];
  #pragma unroll
  for (int nt = 0; nt < 4; ++nt) {
    b1v[nt] = b1[nt*16 + l16];
    w2v[nt] = W2[nt*16 + l16];
  }
  #pragma unroll
  for (int mt = 0; mt < 2; ++mt)
    #pragma unroll
    for (int rr = 0; rr < 4; ++rr) {
      float h = 0.f;
      #pragma unroll
      for (int nt = 0; nt < 4; ++nt)
        h += fmaxf(acc[mt][nt][rr] + b1v[nt], 0.f) * w2v[nt];
      #pragma unroll
      for (int o = 1; o < 16; o <<= 1) h += __shfl_xor(h, o);
      if (l16 == 0)
        e2out[m0 + wid*32 + mt*16 + quad*4 + rr] = h;
    }
}

// ---------------- fused row-softmax + weighted column-sum (bf16 E) --------
__global__ __launch_bounds__(256) void fused_sm_kernel(
    const ushort* __restrict__ E, const float* __restrict__ w,
    float* __restrict__ u_part)
{
  __shared__ float ul[4][1024];
  const int b = blockIdx.y;
  const int strip = blockIdx.x;       // 0..63
  const int t = threadIdx.x, wv = t >> 6, lane = t & 63;
  const ushort* Eb = E + (size_t)b*C_*C_;
  const float* wb = w + (size_t)b*C_;
  float acc[2][8] = {};               // i = c*512 + lane*8 + k
  #pragma unroll
  for (int rj = 0; rj < 4; ++rj) {
    const int j = strip*16 + wv*4 + rj;
    const ushort* row = Eb + (size_t)j*C_;
    float vv[2][8];
    float m = -1e30f;
    #pragma unroll
    for (int c = 0; c < 2; ++c) {
      ushortx8 h = *(const ushortx8*)&row[c*512 + lane*8];
      #pragma unroll
      for (int kk = 0; kk < 8; ++kk) {
        vv[c][kk] = bf2f(h[kk]);
        m = fmaxf(m, vv[c][kk]);
      }
    }
    m = wave_max(m);
    float e[2][8];
    float s = 0.f;
    #pragma unroll
    for (int c = 0; c < 2; ++c)
      #pragma unroll
      for (int kk = 0; kk < 8; ++kk) {
        e[c][kk] = expf(vv[c][kk] - m);
        s += e[c][kk];
      }
    s = wave_sum(s);
    const float sc = wb[j] / s;
    #pragma unroll
    for (int c = 0; c < 2; ++c)
      #pragma unroll
      for (int kk = 0; kk < 8; ++kk) acc[c][kk] += sc * e[c][kk];
  }
  #pragma unroll
  for (int c = 0; c < 2; ++c)
    #pragma unroll
    for (int k4 = 0; k4 < 2; ++k4) {
      float4 o;
      o.x = acc[c][k4*4+0]; o.y = acc[c][k4*4+1];
      o.z = acc[c][k4*4+2]; o.w = acc[c][k4*4+3];
      *(float4*)&ul[wv][c*512 + lane*8 + k4*4] = o;
    }
  __syncthreads();
  float4 r0 = *(float4*)&ul[0][t*4];
  float4 r1 = *(float4*)&ul[1][t*4];
  float4 r2 = *(float4*)&ul[2][t*4];
  float4 r3 = *(float4*)&ul[3][t*4];
  float4 o;
  o.x = r0.x+r1.x+r2.x+r3.x; o.y = r0.y+r1.y+r2.y+r3.y;
  o.z = r0.z+r1.z+r2.z+r3.z; o.w = r0.w+r1.w+r2.w+r3.w;
  *(float4*)&u_part[((size_t)strip*B_ + b)*C_ + t*4] = o;
}

// ---------------- pooling softmax ----------------
__global__ __launch_bounds__(256) void softmax_w_kernel(
    const float* __restrict__ e2in, float* __restrict__ w)
{
  __shared__ float redm[4];
  __shared__ float reds[4];
  const int b = blockIdx.x, t = threadIdx.x;
  const int lane = t & 63, wid = t >> 6;
  const float* row = e2in + (size_t)b*C_;
  float4 v = *(const float4*)&row[t*4];
  float m = fmaxf(fmaxf(v.x, v.y), fmaxf(v.z, v.w));
  m = wave_max(m);
  if (lane == 0) redm[wid] = m;
  __syncthreads();
  m = fmaxf(fmaxf(redm[0], redm[1]), fmaxf(redm[2], redm[3]));
  float e0 = expf(v.x - m), e1 = expf(v.y - m);
  float e2 = expf(v.z - m), e3 = expf(v.w - m);
  float s = e0 + e1 + e2 + e3;
  s = wave_sum(s);
  if (lane == 0) reds[wid] = s;
  __syncthreads();
  s = reds[0] + reds[1] + reds[2] + reds[3];
  const float inv = 1.0f / s;
  float4 o; o.x = e0*inv; o.y = e1*inv; o.z = e2*inv; o.w = e3*inv;
  *(float4*)&w[(size_t)b*C_ + t*4] = o;
}

// ---------------- final: u-combine fused, atomicAdd into pre-zeroed out ---
__global__ __launch_bounds__(256) void final_part_kernel(
    const ushort* __restrict__ X, const ushort* __restrict__ V,
    const float* __restrict__ u_part, const float* __restrict__ w,
    const float* __restrict__ gamma, float* __restrict__ out)
{
  const int b = blockIdx.x, s = blockIdx.y;    // i in [s*16, s*16+16)
  const int t = threadIdx.x;
  __shared__ float red[16][17];
  __shared__ float us[16];
  {
    const int ii = t & 15, g = t >> 4;         // g sums 4 strips
    float p = 0.f;
    #pragma unroll
    for (int q2 = 0; q2 < 4; ++q2) {
      const int sp = g*4 + q2;
      p += u_part[((size_t)sp*B_ + b)*C_ + s*16 + ii];
    }
    red[ii][g] = p;
  }
  __syncthreads();
  if (t < 16) {
    float s2 = 0.f;
    #pragma unroll
    for (int g = 0; g < 16; ++g) s2 += red[t][g];
    us[t] = s2;
  }
  __syncthreads();

  const int d0 = t * 4;
  const ushort* xb = X + (size_t)b*C_*D_;
  const ushort* vb = V + (size_t)b*C_*D_;
  const float* wb = w + (size_t)b*C_;
  float4 av = {0,0,0,0}, ax = {0,0,0,0};
  #pragma unroll
  for (int ii = 0; ii < 16; ++ii) {
    const int i = s*16 + ii;
    const float ui = us[ii], wi = wb[i];
    ushort4 vv = *(const ushort4*)&vb[(size_t)i*D_ + d0];
    ushort4 xv = *(const ushort4*)&xb[(size_t)i*D_ + d0];
    av.x += ui*bf2f(vv.x); av.y += ui*bf2f(vv.y);
    av.z += ui*bf2f(vv.z); av.w += ui*bf2f(vv.w);
    ax.x += wi*bf2f(xv.x); ax.y += wi*bf2f(xv.y);
    ax.z += wi*bf2f(xv.z); ax.w += wi*bf2f(xv.w);
  }
  const float g = gamma[0];
  float* op = out + (size_t)b*D_ + d0;
  atomicAdd(op + 0, g*av.x + ax.x);
  atomicAdd(op + 1, g*av.y + ax.y);
  atomicAdd(op + 2, g*av.z + ax.z);
  atomicAdd(op + 3, g*av.w + ax.w);
}

extern "C" void kernel_launch(void* const* d_in, const int* in_sizes, int n_in,
                              void* d_out, int out_size, void* d_ws, size_t ws_size,
                              hipStream_t stream) {
  (void)in_sizes; (void)n_in; (void)out_size; (void)ws_size;
  const float* x  = (const float*)d_in[0];
  const float* Wf = (const float*)d_in[1];
  const float* bf = (const float*)d_in[2];
  const float* Wg = (const float*)d_in[3];
  const float* bg = (const float*)d_in[4];
  const float* Wx = (const float*)d_in[5];
  const float* bx = (const float*)d_in[6];
  const float* W1 = (const float*)d_in[7];
  const float* b1 = (const float*)d_in[8];
  const float* W2 = (const float*)d_in[9];
  const float* gamma = (const float*)d_in[11];
  float* out = (float*)d_out;

  // workspace layout (~140 MB total)
  ushort* x_bf = (ushort*)d_ws;                  // 32 MB
  ushort* wt   = x_bf + (size_t)M_*D_;           // 6 MB (Wf^T|Wg^T|Wx^T contiguous)
  ushort* w1t  = wt + (size_t)3*D_*D_;           // 128 KB
  ushort* q_bf = w1t + (size_t)H_*D_;            // 32 MB
  ushort* k_bf = q_bf + (size_t)M_*D_;           // 32 MB
  ushort* v_bf = k_bf + (size_t)M_*D_;           // 32 MB
  ushort* E    = v_bf + (size_t)M_*D_;           // 32 MB (bf16, all batches)
  float*  e2b  = (float*)(E + (size_t)B_*C_*C_); // 64 KB
  float*  wbuf = e2b + M_;                       // 64 KB
  float*  u_part = wbuf + M_;                    // 4 MB

  // prep: x->bf16 + weight transposes + zero(out), one launch
  prep_kernel<<<dim3(16384+3072+64+16), 256, 0, stream>>>(
      x, Wf, Wg, Wx, W1, x_bf, wt, w1t, out);

  // merged q/k/v projection (bf16 MFMA, N=3072, BK=64, XCD-swizzled)
  proj_kernel<<<dim3(24,128), 256, 0, stream>>>(x_bf, wt, bf, bg, bx,
                                                q_bf, k_bf, v_bf);

  // pooling weights (MFMA MLP + softmax)
  pool_mfma_kernel<<<dim3(M_/128), 256, 0, stream>>>(x_bf, w1t, b1, W2, e2b);
  softmax_w_kernel<<<dim3(B_), 256, 0, stream>>>(e2b, wbuf);

  // energy (bf16 MFMA, bf16 out, BK=64, XCD-swizzled) + fused softmax/colsum
  energy_kernel<<<dim3(8,8,B_), 256, 0, stream>>>(k_bf, q_bf, E);
  fused_sm_kernel<<<dim3(64,B_), 256, 0, stream>>>(E, wbuf, u_part);

  // final: u-combine + split-i reduction, atomicAdd into zeroed out
  final_part_kernel<<<dim3(B_,64), 256, 0, stream>>>(x_bf, v_bf, u_part, wbuf,
                                                     gamma, out);
}

// Round 9
// 329.720 us; speedup vs baseline: 1.0398x; 1.0398x over previous
//
#include <hip/hip_runtime.h>

#define B_ 16
#define C_ 1024
#define D_ 1024
#define H_ 64
#define M_ (B_*C_)   // 16384

typedef __attribute__((ext_vector_type(8))) short bf16x8;
typedef __attribute__((ext_vector_type(8))) unsigned short ushortx8;
typedef __attribute__((ext_vector_type(4))) float f32x4;

__device__ __forceinline__ float wave_max(float v){
  #pragma unroll
  for (int o = 32; o > 0; o >>= 1) v = fmaxf(v, __shfl_xor(v, o));
  return v;
}
__device__ __forceinline__ float wave_sum(float v){
  #pragma unroll
  for (int o = 32; o > 0; o >>= 1) v += __shfl_xor(v, o);
  return v;
}

// fp32 -> bf16 (RNE)
__device__ __forceinline__ ushort f2bf(float f){
  union { float f; unsigned u; } a; a.f = f;
  unsigned r = a.u + 0x7fff + ((a.u >> 16) & 1);
  return (ushort)(r >> 16);
}
__device__ __forceinline__ float bf2f(ushort h){
  union { unsigned u; float f; } a; a.u = ((unsigned)h) << 16; return a.f;
}

// async global->LDS, 16 B per lane; LDS dest is wave-uniform base + lane*16.
__device__ __forceinline__ void lds_cp16(const ushort* g, ushort* l){
  __builtin_amdgcn_global_load_lds(
      (const __attribute__((address_space(1))) void*)g,
      (__attribute__((address_space(3))) void*)l, 16, 0, 0);
}

// ---------------- merged prep: cvt(x) + weight transposes -----------------
__global__ __launch_bounds__(256) void prep_kernel(
    const float* __restrict__ x, const float* __restrict__ Wf,
    const float* __restrict__ Wg, const float* __restrict__ Wx,
    const float* __restrict__ W1,
    ushort* __restrict__ x_bf, ushort* __restrict__ wt,
    ushort* __restrict__ w1t)
{
  __shared__ float tile[32][33];
  const int blk = blockIdx.x;
  const int t = threadIdx.x;
  if (blk < 16384) {                       // cvt: x -> bf16, 4 elems/thread
    const int i = blk*256 + t;
    float4 v = ((const float4*)x)[i];
    ushort4 o;
    o.x = f2bf(v.x); o.y = f2bf(v.y); o.z = f2bf(v.z); o.w = f2bf(v.w);
    ((ushort4*)x_bf)[i] = o;
  } else if (blk < 16384 + 3072) {         // tconv of Wf/Wg/Wx -> wt[z]
    const int bb = blk - 16384;
    const int z = bb >> 10, rem = bb & 1023;
    const int n0 = (rem & 31)*32, k0 = (rem >> 5)*32;
    const float* W = (z == 0) ? Wf : (z == 1) ? Wg : Wx;
    ushort* Out = wt + (size_t)z*D_*D_;
    const int tx = t & 31, ty = t >> 5;
    #pragma unroll
    for (int i = 0; i < 32; i += 8)
      tile[ty+i][tx] = W[(size_t)(k0+ty+i)*D_ + n0+tx];
    __syncthreads();
    #pragma unroll
    for (int i = 0; i < 32; i += 8)
      Out[(size_t)(n0+ty+i)*D_ + k0+tx] = f2bf(tile[tx][ty+i]);
  } else {                                 // tconv of W1 (1024x64) -> w1t
    const int bb = blk - 16384 - 3072;
    const int n0 = (bb & 1)*32, k0 = (bb >> 1)*32;
    const int tx = t & 31, ty = t >> 5;
    #pragma unroll
    for (int i = 0; i < 32; i += 8)
      tile[ty+i][tx] = W1[(size_t)(k0+ty+i)*H_ + n0+tx];
    __syncthreads();
    #pragma unroll
    for (int i = 0; i < 32; i += 8)
      w1t[(size_t)(n0+ty+i)*D_ + k0+tx] = f2bf(tile[tx][ty+i]);
  }
}

// ---------------- merged QKV projection: NT GEMM, N=3072, BK=64 -----------
// BK=64 (half the barrier pairs of BK=32), XOR k-chunk swizzle -> 0 LDS
// conflicts, __launch_bounds__(256,3) -> 3 blocks/CU so one block's MFMA
// covers another's vmcnt drain at the barrier.
__global__ __launch_bounds__(256, 3) void proj_kernel(
    const ushort* __restrict__ A, const ushort* __restrict__ Wt,
    const float* __restrict__ bf, const float* __restrict__ bg,
    const float* __restrict__ bx,
    ushort* __restrict__ q, ushort* __restrict__ k, ushort* __restrict__ v)
{
  __shared__ ushort As[128*64];
  __shared__ ushort Bs[128*64];
  const int t = threadIdx.x;
  const int wid = t >> 6, lane = t & 63;
  const int m0 = blockIdx.y * 128, n0 = blockIdx.x * 128;   // n0 in [0,3072)
  const int seg = n0 >> 10;                                  // 0:q 1:k 2:v
  const int nloc0 = n0 - (seg << 10);

  const int srow = t >> 3;
  const int sch = ((t & 7) ^ (srow & 7)) * 8;
  const ushort* gaBase = A  + (size_t)(m0 + srow)*1024 + sch;
  const ushort* gbBase = Wt + (size_t)(n0 + srow)*1024 + sch;

  const int quad = lane >> 4, l16 = lane & 15;
  const int wm = wid >> 1, wn = wid & 1;
  const int cx0 = ((0*4 + quad) ^ (l16 & 7)) * 8;
  const int cx1 = ((1*4 + quad) ^ (l16 & 7)) * 8;
  const int arow0 = (wm*64 + l16)*64;
  const int brow0 = (wn*64 + l16)*64;

  f32x4 acc[4][4] = {};

  for (int k0 = 0; k0 < 1024; k0 += 64) {
    #pragma unroll
    for (int i = 0; i < 4; ++i) {
      lds_cp16(gaBase + (size_t)(i*32)*1024, As + (8*wid + 32*i)*64);
      lds_cp16(gbBase + (size_t)(i*32)*1024, Bs + (8*wid + 32*i)*64);
    }
    gaBase += 64; gbBase += 64;
    __syncthreads();
    #pragma unroll
    for (int h = 0; h < 2; ++h) {
      const int cx = h ? cx1 : cx0;
      bf16x8 af[4], bfr[4];
      #pragma unroll
      for (int i = 0; i < 4; ++i) {
        af[i]  = *(const bf16x8*)&As[arow0 + i*1024 + cx];
        bfr[i] = *(const bf16x8*)&Bs[brow0 + i*1024 + cx];
      }
      #pragma unroll
      for (int mt = 0; mt < 4; ++mt)
        #pragma unroll
        for (int nt = 0; nt < 4; ++nt)
          acc[mt][nt] = __builtin_amdgcn_mfma_f32_16x16x32_bf16(
              af[mt], bfr[nt], acc[mt][nt], 0, 0, 0);
    }
    __syncthreads();
  }

  const float* bp = (seg == 0) ? bf : (seg == 1) ? bg : bx;
  ushort* op      = (seg == 0) ? q  : (seg == 1) ? k  : v;
  const int gm_base = m0 + wm*64 + quad*4;
  const int gn_base = nloc0 + wn*64 + l16;
  float bv[4];
  #pragma unroll
  for (int nt = 0; nt < 4; ++nt) bv[nt] = bp[gn_base + nt*16];
  #pragma unroll
  for (int mt = 0; mt < 4; ++mt)
    #pragma unroll
    for (int rr = 0; rr < 4; ++rr) {
      const size_t rowoff = (size_t)(gm_base + mt*16 + rr) * 1024;
      #pragma unroll
      for (int nt = 0; nt < 4; ++nt)
        op[rowoff + gn_base + nt*16] =
            f2bf(fmaxf(acc[mt][nt][rr] + bv[nt], 0.f));
    }
}

// ---------------- energy: NT GEMM, bf16 out, BK=64 ----------------
__global__ __launch_bounds__(256, 3) void energy_kernel(
    const ushort* __restrict__ Km, const ushort* __restrict__ Qm,
    ushort* __restrict__ E)
{
  __shared__ ushort As[128*64];
  __shared__ ushort Bs[128*64];
  const int t = threadIdx.x;
  const int wid = t >> 6, lane = t & 63;
  const int m0 = blockIdx.y * 128, n0 = blockIdx.x * 128;
  const int bz = blockIdx.z;
  const ushort* Ab = Km + (size_t)bz * C_ * D_;
  const ushort* Bb = Qm + (size_t)bz * C_ * D_;

  const int srow = t >> 3;
  const int sch = ((t & 7) ^ (srow & 7)) * 8;
  const ushort* gaBase = Ab + (size_t)(m0 + srow)*1024 + sch;
  const ushort* gbBase = Bb + (size_t)(n0 + srow)*1024 + sch;

  const int quad = lane >> 4, l16 = lane & 15;
  const int wm = wid >> 1, wn = wid & 1;
  const int cx0 = ((0*4 + quad) ^ (l16 & 7)) * 8;
  const int cx1 = ((1*4 + quad) ^ (l16 & 7)) * 8;
  const int arow0 = (wm*64 + l16)*64;
  const int brow0 = (wn*64 + l16)*64;

  f32x4 acc[4][4] = {};

  for (int k0 = 0; k0 < 1024; k0 += 64) {
    #pragma unroll
    for (int i = 0; i < 4; ++i) {
      lds_cp16(gaBase + (size_t)(i*32)*1024, As + (8*wid + 32*i)*64);
      lds_cp16(gbBase + (size_t)(i*32)*1024, Bs + (8*wid + 32*i)*64);
    }
    gaBase += 64; gbBase += 64;
    __syncthreads();
    #pragma unroll
    for (int h = 0; h < 2; ++h) {
      const int cx = h ? cx1 : cx0;
      bf16x8 af[4], bfr[4];
      #pragma unroll
      for (int i = 0; i < 4; ++i) {
        af[i]  = *(const bf16x8*)&As[arow0 + i*1024 + cx];
        bfr[i] = *(const bf16x8*)&Bs[brow0 + i*1024 + cx];
      }
      #pragma unroll
      for (int mt = 0; mt < 4; ++mt)
        #pragma unroll
        for (int nt = 0; nt < 4; ++nt)
          acc[mt][nt] = __builtin_amdgcn_mfma_f32_16x16x32_bf16(
              af[mt], bfr[nt], acc[mt][nt], 0, 0, 0);
    }
    __syncthreads();
  }

  ushort* O = E + (size_t)bz * C_ * C_;
  const int gm_base = m0 + wm*64 + quad*4;
  const int gn_base = n0 + wn*64 + l16;
  #pragma unroll
  for (int mt = 0; mt < 4; ++mt)
    #pragma unroll
    for (int rr = 0; rr < 4; ++rr) {
      const size_t rowoff = (size_t)(gm_base + mt*16 + rr) * 1024;
      #pragma unroll
      for (int nt = 0; nt < 4; ++nt)
        O[rowoff + gn_base + nt*16] = f2bf(acc[mt][nt][rr]);
    }
}

// ---------------- pooling MLP via MFMA (BK=32) ----------------------------
__device__ __forceinline__ int fsw(int row){
  return (row & 3) ^ ((row >> 2) & 3);
}
__global__ __launch_bounds__(256) void pool_mfma_kernel(
    const ushort* __restrict__ A, const ushort* __restrict__ Bt,
    const float* __restrict__ b1, const float* __restrict__ W2,
    float* __restrict__ e2out)
{
  __shared__ ushort As[128*32];
  __shared__ ushort Bs[64*32];
  const int t = threadIdx.x;
  const int wid = t >> 6, lane = t & 63;
  const int m0 = blockIdx.x * 128;

  const int r = t >> 2;
  const int kc = ((t & 3) ^ fsw(r)) * 8;
  const ushort* ga0 = A + (size_t)(m0 + r)*1024 + kc;
  const ushort* ga1 = ga0 + (size_t)64*1024;
  const ushort* gb0 = Bt + (size_t)r*1024 + kc;
  ushort* lA = As + wid*512;
  ushort* lB = Bs + wid*512;

  const int quad = lane >> 4, l16 = lane & 15;
  const int fr = fsw(l16);
  const int am0 = (wid*32 + l16)*32 + ((quad ^ fr)*8);
  const int bn0 = l16*32 + ((quad ^ fr)*8);

  f32x4 acc[2][4] = {};

  for (int k0 = 0; k0 < 1024; k0 += 32) {
    lds_cp16(ga0, lA); lds_cp16(ga1, lA + 2048);
    lds_cp16(gb0, lB);
    ga0 += 32; ga1 += 32; gb0 += 32;
    __syncthreads();
    bf16x8 af[2], bfr[4];
    #pragma unroll
    for (int i = 0; i < 2; ++i) af[i] = *(const bf16x8*)&As[am0 + i*512];
    #pragma unroll
    for (int i = 0; i < 4; ++i) bfr[i] = *(const bf16x8*)&Bs[bn0 + i*512];
    #pragma unroll
    for (int mt = 0; mt < 2; ++mt)
      #pragma unroll
      for (int nt = 0; nt < 4; ++nt)
        acc[mt][nt] = __builtin_amdgcn_mfma_f32_16x16x32_bf16(
            af[mt], bfr[nt], acc[mt][nt], 0, 0, 0);
    __syncthreads();
  }

  float b1v[4], w2v[4];
  #pragma unroll
  for (int nt = 0; nt < 4; ++nt) {
    b1v[nt] = b1[nt*16 + l16];
    w2v[nt] = W2[nt*16 + l16];
  }
  #pragma unroll
  for (int mt = 0; mt < 2; ++mt)
    #pragma unroll
    for (int rr = 0; rr < 4; ++rr) {
      float h = 0.f;
      #pragma unroll
      for (int nt = 0; nt < 4; ++nt)
        h += fmaxf(acc[mt][nt][rr] + b1v[nt], 0.f) * w2v[nt];
      #pragma unroll
      for (int o = 1; o < 16; o <<= 1) h += __shfl_xor(h, o);
      if (l16 == 0)
        e2out[m0 + wid*32 + mt*16 + quad*4 + rr] = h;
    }
}

// ---------------- fused row-softmax + weighted column-sum (bf16 E) --------
__global__ __launch_bounds__(256) void fused_sm_kernel(
    const ushort* __restrict__ E, const float* __restrict__ w,
    float* __restrict__ u_part)
{
  __shared__ float ul[4][1024];
  const int b = blockIdx.y;
  const int strip = blockIdx.x;       // 0..63
  const int t = threadIdx.x, wv = t >> 6, lane = t & 63;
  const ushort* Eb = E + (size_t)b*C_*C_;
  const float* wb = w + (size_t)b*C_;
  float acc[2][8] = {};               // i = c*512 + lane*8 + k
  #pragma unroll
  for (int rj = 0; rj < 4; ++rj) {
    const int j = strip*16 + wv*4 + rj;
    const ushort* row = Eb + (size_t)j*C_;
    float vv[2][8];
    float m = -1e30f;
    #pragma unroll
    for (int c = 0; c < 2; ++c) {
      ushortx8 h = *(const ushortx8*)&row[c*512 + lane*8];
      #pragma unroll
      for (int kk = 0; kk < 8; ++kk) {
        vv[c][kk] = bf2f(h[kk]);
        m = fmaxf(m, vv[c][kk]);
      }
    }
    m = wave_max(m);
    float e[2][8];
    float s = 0.f;
    #pragma unroll
    for (int c = 0; c < 2; ++c)
      #pragma unroll
      for (int kk = 0; kk < 8; ++kk) {
        e[c][kk] = expf(vv[c][kk] - m);
        s += e[c][kk];
      }
    s = wave_sum(s);
    const float sc = wb[j] / s;
    #pragma unroll
    for (int c = 0; c < 2; ++c)
      #pragma unroll
      for (int kk = 0; kk < 8; ++kk) acc[c][kk] += sc * e[c][kk];
  }
  #pragma unroll
  for (int c = 0; c < 2; ++c)
    #pragma unroll
    for (int k4 = 0; k4 < 2; ++k4) {
      float4 o;
      o.x = acc[c][k4*4+0]; o.y = acc[c][k4*4+1];
      o.z = acc[c][k4*4+2]; o.w = acc[c][k4*4+3];
      *(float4*)&ul[wv][c*512 + lane*8 + k4*4] = o;
    }
  __syncthreads();
  float4 r0 = *(float4*)&ul[0][t*4];
  float4 r1 = *(float4*)&ul[1][t*4];
  float4 r2 = *(float4*)&ul[2][t*4];
  float4 r3 = *(float4*)&ul[3][t*4];
  float4 o;
  o.x = r0.x+r1.x+r2.x+r3.x; o.y = r0.y+r1.y+r2.y+r3.y;
  o.z = r0.z+r1.z+r2.z+r3.z; o.w = r0.w+r1.w+r2.w+r3.w;
  *(float4*)&u_part[((size_t)strip*B_ + b)*C_ + t*4] = o;
}

// ---------------- pooling softmax ----------------
__global__ __launch_bounds__(256) void softmax_w_kernel(
    const float* __restrict__ e2in, float* __restrict__ w)
{
  __shared__ float redm[4];
  __shared__ float reds[4];
  const int b = blockIdx.x, t = threadIdx.x;
  const int lane = t & 63, wid = t >> 6;
  const float* row = e2in + (size_t)b*C_;
  float4 v = *(const float4*)&row[t*4];
  float m = fmaxf(fmaxf(v.x, v.y), fmaxf(v.z, v.w));
  m = wave_max(m);
  if (lane == 0) redm[wid] = m;
  __syncthreads();
  m = fmaxf(fmaxf(redm[0], redm[1]), fmaxf(redm[2], redm[3]));
  float e0 = expf(v.x - m), e1 = expf(v.y - m);
  float e2 = expf(v.z - m), e3 = expf(v.w - m);
  float s = e0 + e1 + e2 + e3;
  s = wave_sum(s);
  if (lane == 0) reds[wid] = s;
  __syncthreads();
  s = reds[0] + reds[1] + reds[2] + reds[3];
  const float inv = 1.0f / s;
  float4 o; o.x = e0*inv; o.y = e1*inv; o.z = e2*inv; o.w = e3*inv;
  *(float4*)&w[(size_t)b*C_ + t*4] = o;
}

// ---------------- final reduction: u-combine fused in, split over i -------
__global__ __launch_bounds__(256) void final_part_kernel(
    const ushort* __restrict__ X, const ushort* __restrict__ V,
    const float* __restrict__ u_part, const float* __restrict__ w,
    const float* __restrict__ gamma, float* __restrict__ fpart)
{
  const int b = blockIdx.x, s = blockIdx.y;    // i in [s*16, s*16+16)
  const int t = threadIdx.x;
  __shared__ float red[16][17];
  __shared__ float us[16];
  {
    const int ii = t & 15, g = t >> 4;         // g sums 4 strips
    float p = 0.f;
    #pragma unroll
    for (int q2 = 0; q2 < 4; ++q2) {
      const int sp = g*4 + q2;
      p += u_part[((size_t)sp*B_ + b)*C_ + s*16 + ii];
    }
    red[ii][g] = p;
  }
  __syncthreads();
  if (t < 16) {
    float s2 = 0.f;
    #pragma unroll
    for (int g = 0; g < 16; ++g) s2 += red[t][g];
    us[t] = s2;
  }
  __syncthreads();

  const int d0 = t * 4;
  const ushort* xb = X + (size_t)b*C_*D_;
  const ushort* vb = V + (size_t)b*C_*D_;
  const float* wb = w + (size_t)b*C_;
  float4 av = {0,0,0,0}, ax = {0,0,0,0};
  #pragma unroll
  for (int ii = 0; ii < 16; ++ii) {
    const int i = s*16 + ii;
    const float ui = us[ii], wi = wb[i];
    ushort4 vv = *(const ushort4*)&vb[(size_t)i*D_ + d0];
    ushort4 xv = *(const ushort4*)&xb[(size_t)i*D_ + d0];
    av.x += ui*bf2f(vv.x); av.y += ui*bf2f(vv.y);
    av.z += ui*bf2f(vv.z); av.w += ui*bf2f(vv.w);
    ax.x += wi*bf2f(xv.x); ax.y += wi*bf2f(xv.y);
    ax.z += wi*bf2f(xv.z); ax.w += wi*bf2f(xv.w);
  }
  const float g = gamma[0];
  float4 o;
  o.x = g*av.x + ax.x; o.y = g*av.y + ax.y;
  o.z = g*av.z + ax.z; o.w = g*av.w + ax.w;
  *(float4*)&fpart[((size_t)s*B_ + b)*D_ + d0] = o;
}

__global__ __launch_bounds__(256) void final_combine_kernel(
    const float* __restrict__ fpart, float* __restrict__ out)
{
  const int idx = blockIdx.x*256 + threadIdx.x;   // over B_*D_
  float s = 0.f;
  #pragma unroll 8
  for (int sp = 0; sp < 64; ++sp) s += fpart[(size_t)sp*B_*D_ + idx];
  out[idx] = s;
}

extern "C" void kernel_launch(void* const* d_in, const int* in_sizes, int n_in,
                              void* d_out, int out_size, void* d_ws, size_t ws_size,
                              hipStream_t stream) {
  (void)in_sizes; (void)n_in; (void)out_size; (void)ws_size;
  const float* x  = (const float*)d_in[0];
  const float* Wf = (const float*)d_in[1];
  const float* bf = (const float*)d_in[2];
  const float* Wg = (const float*)d_in[3];
  const float* bg = (const float*)d_in[4];
  const float* Wx = (const float*)d_in[5];
  const float* bx = (const float*)d_in[6];
  const float* W1 = (const float*)d_in[7];
  const float* b1 = (const float*)d_in[8];
  const float* W2 = (const float*)d_in[9];
  const float* gamma = (const float*)d_in[11];
  float* out = (float*)d_out;

  // workspace layout (~140 MB total)
  ushort* x_bf = (ushort*)d_ws;                  // 32 MB
  ushort* wt   = x_bf + (size_t)M_*D_;           // 6 MB (Wf^T|Wg^T|Wx^T contiguous)
  ushort* w1t  = wt + (size_t)3*D_*D_;           // 128 KB
  ushort* q_bf = w1t + (size_t)H_*D_;            // 32 MB
  ushort* k_bf = q_bf + (size_t)M_*D_;           // 32 MB
  ushort* v_bf = k_bf + (size_t)M_*D_;           // 32 MB
  ushort* E    = v_bf + (size_t)M_*D_;           // 32 MB (bf16, all batches)
  float*  e2b  = (float*)(E + (size_t)B_*C_*C_); // 64 KB
  float*  wbuf = e2b + M_;                       // 64 KB
  float*  u_part = wbuf + M_;                    // 4 MB
  float*  fpart  = (float*)E;                    // alias: E dead after fused_sm

  // prep: x->bf16 + weight transposes, one launch
  prep_kernel<<<dim3(16384+3072+64), 256, 0, stream>>>(
      x, Wf, Wg, Wx, W1, x_bf, wt, w1t);

  // merged q/k/v projection (bf16 MFMA, N=3072, BK=64, 3 blocks/CU)
  proj_kernel<<<dim3(24,128), 256, 0, stream>>>(x_bf, wt, bf, bg, bx,
                                                q_bf, k_bf, v_bf);

  // pooling weights (MFMA MLP + softmax)
  pool_mfma_kernel<<<dim3(M_/128), 256, 0, stream>>>(x_bf, w1t, b1, W2, e2b);
  softmax_w_kernel<<<dim3(B_), 256, 0, stream>>>(e2b, wbuf);

  // energy (bf16 MFMA, bf16 out, BK=64, 3 blocks/CU) + fused softmax/colsum
  energy_kernel<<<dim3(8,8,B_), 256, 0, stream>>>(k_bf, q_bf, E);
  fused_sm_kernel<<<dim3(64,B_), 256, 0, stream>>>(E, wbuf, u_part);

  // final: u-combine + split-i reduction into fpart, then combine
  final_part_kernel<<<dim3(B_,64), 256, 0, stream>>>(x_bf, v_bf, u_part, wbuf,
                                                     gamma, fpart);
  final_combine_kernel<<<dim3(M_/256), 256, 0, stream>>>(fpart, out);
}

// Round 10
// 323.402 us; speedup vs baseline: 1.0601x; 1.0195x over previous
//
#include <hip/hip_runtime.h>

#define B_ 16
#define C_ 1024
#define D_ 1024
#define H_ 64
#define M_ (B_*C_)   // 16384

typedef __attribute__((ext_vector_type(8))) short bf16x8;
typedef __attribute__((ext_vector_type(8))) unsigned short ushortx8;
typedef __attribute__((ext_vector_type(4))) float f32x4;

__device__ __forceinline__ float wave_max(float v){
  #pragma unroll
  for (int o = 32; o > 0; o >>= 1) v = fmaxf(v, __shfl_xor(v, o));
  return v;
}
__device__ __forceinline__ float wave_sum(float v){
  #pragma unroll
  for (int o = 32; o > 0; o >>= 1) v += __shfl_xor(v, o);
  return v;
}

// fp32 -> bf16 (RNE)
__device__ __forceinline__ ushort f2bf(float f){
  union { float f; unsigned u; } a; a.f = f;
  unsigned r = a.u + 0x7fff + ((a.u >> 16) & 1);
  return (ushort)(r >> 16);
}
__device__ __forceinline__ float bf2f(ushort h){
  union { unsigned u; float f; } a; a.u = ((unsigned)h) << 16; return a.f;
}

// async global->LDS, 16 B per lane; LDS dest is wave-uniform base + lane*16.
__device__ __forceinline__ void lds_cp16(const ushort* g, ushort* l){
  __builtin_amdgcn_global_load_lds(
      (const __attribute__((address_space(1))) void*)g,
      (__attribute__((address_space(3))) void*)l, 16, 0, 0);
}

// ---------------- merged prep: cvt(x) + weight transposes -----------------
__global__ __launch_bounds__(256) void prep_kernel(
    const float* __restrict__ x, const float* __restrict__ Wf,
    const float* __restrict__ Wg, const float* __restrict__ Wx,
    const float* __restrict__ W1,
    ushort* __restrict__ x_bf, ushort* __restrict__ wt,
    ushort* __restrict__ w1t)
{
  __shared__ float tile[32][33];
  const int blk = blockIdx.x;
  const int t = threadIdx.x;
  if (blk < 16384) {                       // cvt: x -> bf16, 4 elems/thread
    const int i = blk*256 + t;
    float4 v = ((const float4*)x)[i];
    ushort4 o;
    o.x = f2bf(v.x); o.y = f2bf(v.y); o.z = f2bf(v.z); o.w = f2bf(v.w);
    ((ushort4*)x_bf)[i] = o;
  } else if (blk < 16384 + 3072) {         // tconv of Wf/Wg/Wx -> wt[z]
    const int bb = blk - 16384;
    const int z = bb >> 10, rem = bb & 1023;
    const int n0 = (rem & 31)*32, k0 = (rem >> 5)*32;
    const float* W = (z == 0) ? Wf : (z == 1) ? Wg : Wx;
    ushort* Out = wt + (size_t)z*D_*D_;
    const int tx = t & 31, ty = t >> 5;
    #pragma unroll
    for (int i = 0; i < 32; i += 8)
      tile[ty+i][tx] = W[(size_t)(k0+ty+i)*D_ + n0+tx];
    __syncthreads();
    #pragma unroll
    for (int i = 0; i < 32; i += 8)
      Out[(size_t)(n0+ty+i)*D_ + k0+tx] = f2bf(tile[tx][ty+i]);
  } else {                                 // tconv of W1 (1024x64) -> w1t
    const int bb = blk - 16384 - 3072;
    const int n0 = (bb & 1)*32, k0 = (bb >> 1)*32;
    const int tx = t & 31, ty = t >> 5;
    #pragma unroll
    for (int i = 0; i < 32; i += 8)
      tile[ty+i][tx] = W1[(size_t)(k0+ty+i)*H_ + n0+tx];
    __syncthreads();
    #pragma unroll
    for (int i = 0; i < 32; i += 8)
      w1t[(size_t)(n0+ty+i)*D_ + k0+tx] = f2bf(tile[tx][ty+i]);
  }
}

// ---------------- merged QKV projection: NT GEMM, N=3072, BK=64 -----------
// 3072 blocks at 3/CU = exactly 4 scheduling rounds, no tail. Zero LDS
// conflicts via XOR k-chunk swizzle; 981 TF measured (R9).
__global__ __launch_bounds__(256, 3) void proj_kernel(
    const ushort* __restrict__ A, const ushort* __restrict__ Wt,
    const float* __restrict__ bf, const float* __restrict__ bg,
    const float* __restrict__ bx,
    ushort* __restrict__ q, ushort* __restrict__ k, ushort* __restrict__ v)
{
  __shared__ ushort As[128*64];
  __shared__ ushort Bs[128*64];
  const int t = threadIdx.x;
  const int wid = t >> 6, lane = t & 63;
  const int m0 = blockIdx.y * 128, n0 = blockIdx.x * 128;   // n0 in [0,3072)
  const int seg = n0 >> 10;                                  // 0:q 1:k 2:v
  const int nloc0 = n0 - (seg << 10);

  const int srow = t >> 3;
  const int sch = ((t & 7) ^ (srow & 7)) * 8;
  const ushort* gaBase = A  + (size_t)(m0 + srow)*1024 + sch;
  const ushort* gbBase = Wt + (size_t)(n0 + srow)*1024 + sch;

  const int quad = lane >> 4, l16 = lane & 15;
  const int wm = wid >> 1, wn = wid & 1;
  const int cx0 = ((0*4 + quad) ^ (l16 & 7)) * 8;
  const int cx1 = ((1*4 + quad) ^ (l16 & 7)) * 8;
  const int arow0 = (wm*64 + l16)*64;
  const int brow0 = (wn*64 + l16)*64;

  f32x4 acc[4][4] = {};

  for (int k0 = 0; k0 < 1024; k0 += 64) {
    #pragma unroll
    for (int i = 0; i < 4; ++i) {
      lds_cp16(gaBase + (size_t)(i*32)*1024, As + (8*wid + 32*i)*64);
      lds_cp16(gbBase + (size_t)(i*32)*1024, Bs + (8*wid + 32*i)*64);
    }
    gaBase += 64; gbBase += 64;
    __syncthreads();
    #pragma unroll
    for (int h = 0; h < 2; ++h) {
      const int cx = h ? cx1 : cx0;
      bf16x8 af[4], bfr[4];
      #pragma unroll
      for (int i = 0; i < 4; ++i) {
        af[i]  = *(const bf16x8*)&As[arow0 + i*1024 + cx];
        bfr[i] = *(const bf16x8*)&Bs[brow0 + i*1024 + cx];
      }
      #pragma unroll
      for (int mt = 0; mt < 4; ++mt)
        #pragma unroll
        for (int nt = 0; nt < 4; ++nt)
          acc[mt][nt] = __builtin_amdgcn_mfma_f32_16x16x32_bf16(
              af[mt], bfr[nt], acc[mt][nt], 0, 0, 0);
    }
    __syncthreads();
  }

  const float* bp = (seg == 0) ? bf : (seg == 1) ? bg : bx;
  ushort* op      = (seg == 0) ? q  : (seg == 1) ? k  : v;
  const int gm_base = m0 + wm*64 + quad*4;
  const int gn_base = nloc0 + wn*64 + l16;
  float bv[4];
  #pragma unroll
  for (int nt = 0; nt < 4; ++nt) bv[nt] = bp[gn_base + nt*16];
  #pragma unroll
  for (int mt = 0; mt < 4; ++mt)
    #pragma unroll
    for (int rr = 0; rr < 4; ++rr) {
      const size_t rowoff = (size_t)(gm_base + mt*16 + rr) * 1024;
      #pragma unroll
      for (int nt = 0; nt < 4; ++nt)
        op[rowoff + gn_base + nt*16] =
            f2bf(fmaxf(acc[mt][nt][rr] + bv[nt], 0.f));
    }
}

// ---------------- energy: NT GEMM, 64x128 tile, BK=64, 4 blocks/CU --------
// Grid = 16x8x16 = 2048 blocks; at 4/CU -> 1024 co-resident = exactly 2
// scheduling rounds (the 128x128 version was 1024 blocks at 3/CU = 1.33
// rounds -> 256-block straggler tail). Wave w owns n-cols [w*32, w*32+32).
__global__ __launch_bounds__(256, 4) void energy_kernel(
    const ushort* __restrict__ Km, const ushort* __restrict__ Qm,
    ushort* __restrict__ E)
{
  __shared__ ushort As[64*64];    // [m(j) row][k]
  __shared__ ushort Bs[128*64];   // [n(i) row][k]
  const int t = threadIdx.x;
  const int wid = t >> 6, lane = t & 63;
  const int m0 = blockIdx.y * 64, n0 = blockIdx.x * 128;
  const int bz = blockIdx.z;
  const ushort* Ab = Km + (size_t)bz * C_ * D_;
  const ushort* Bb = Qm + (size_t)bz * C_ * D_;

  const int srow = t >> 3;                      // 0..31
  const int sch = ((t & 7) ^ (srow & 7)) * 8;   // +32 rows keeps row&7
  const ushort* gaBase = Ab + (size_t)(m0 + srow)*1024 + sch;
  const ushort* gbBase = Bb + (size_t)(n0 + srow)*1024 + sch;

  const int quad = lane >> 4, l16 = lane & 15;
  const int cx0 = ((0*4 + quad) ^ (l16 & 7)) * 8;
  const int cx1 = ((1*4 + quad) ^ (l16 & 7)) * 8;
  const int brow0 = (wid*32 + l16)*64;

  f32x4 acc[4][2] = {};

  for (int k0 = 0; k0 < 1024; k0 += 64) {
    // A: 64 rows -> 2 issues; B: 128 rows -> 4 issues
    #pragma unroll
    for (int i = 0; i < 2; ++i)
      lds_cp16(gaBase + (size_t)(i*32)*1024, As + (8*wid + 32*i)*64);
    #pragma unroll
    for (int i = 0; i < 4; ++i)
      lds_cp16(gbBase + (size_t)(i*32)*1024, Bs + (8*wid + 32*i)*64);
    gaBase += 64; gbBase += 64;
    __syncthreads();
    #pragma unroll
    for (int h = 0; h < 2; ++h) {
      const int cx = h ? cx1 : cx0;
      bf16x8 af[4], bfr[2];
      #pragma unroll
      for (int i = 0; i < 4; ++i)
        af[i] = *(const bf16x8*)&As[(i*16 + l16)*64 + cx];
      #pragma unroll
      for (int i = 0; i < 2; ++i)
        bfr[i] = *(const bf16x8*)&Bs[brow0 + i*16*64 + cx];
      #pragma unroll
      for (int mt = 0; mt < 4; ++mt)
        #pragma unroll
        for (int nt = 0; nt < 2; ++nt)
          acc[mt][nt] = __builtin_amdgcn_mfma_f32_16x16x32_bf16(
              af[mt], bfr[nt], acc[mt][nt], 0, 0, 0);
    }
    __syncthreads();
  }

  ushort* O = E + (size_t)bz * C_ * C_;
  const int gm_base = m0 + quad*4;              // j row
  const int gn_base = n0 + wid*32 + l16;        // i col
  #pragma unroll
  for (int mt = 0; mt < 4; ++mt)
    #pragma unroll
    for (int rr = 0; rr < 4; ++rr) {
      const size_t rowoff = (size_t)(gm_base + mt*16 + rr) * 1024;
      #pragma unroll
      for (int nt = 0; nt < 2; ++nt)
        O[rowoff + gn_base + nt*16] = f2bf(acc[mt][nt][rr]);
    }
}

// ---------------- pooling MLP via MFMA (BK=32) ----------------------------
__device__ __forceinline__ int fsw(int row){
  return (row & 3) ^ ((row >> 2) & 3);
}
__global__ __launch_bounds__(256) void pool_mfma_kernel(
    const ushort* __restrict__ A, const ushort* __restrict__ Bt,
    const float* __restrict__ b1, const float* __restrict__ W2,
    float* __restrict__ e2out)
{
  __shared__ ushort As[128*32];
  __shared__ ushort Bs[64*32];
  const int t = threadIdx.x;
  const int wid = t >> 6, lane = t & 63;
  const int m0 = blockIdx.x * 128;

  const int r = t >> 2;
  const int kc = ((t & 3) ^ fsw(r)) * 8;
  const ushort* ga0 = A + (size_t)(m0 + r)*1024 + kc;
  const ushort* ga1 = ga0 + (size_t)64*1024;
  const ushort* gb0 = Bt + (size_t)r*1024 + kc;
  ushort* lA = As + wid*512;
  ushort* lB = Bs + wid*512;

  const int quad = lane >> 4, l16 = lane & 15;
  const int fr = fsw(l16);
  const int am0 = (wid*32 + l16)*32 + ((quad ^ fr)*8);
  const int bn0 = l16*32 + ((quad ^ fr)*8);

  f32x4 acc[2][4] = {};

  for (int k0 = 0; k0 < 1024; k0 += 32) {
    lds_cp16(ga0, lA); lds_cp16(ga1, lA + 2048);
    lds_cp16(gb0, lB);
    ga0 += 32; ga1 += 32; gb0 += 32;
    __syncthreads();
    bf16x8 af[2], bfr[4];
    #pragma unroll
    for (int i = 0; i < 2; ++i) af[i] = *(const bf16x8*)&As[am0 + i*512];
    #pragma unroll
    for (int i = 0; i < 4; ++i) bfr[i] = *(const bf16x8*)&Bs[bn0 + i*512];
    #pragma unroll
    for (int mt = 0; mt < 2; ++mt)
      #pragma unroll
      for (int nt = 0; nt < 4; ++nt)
        acc[mt][nt] = __builtin_amdgcn_mfma_f32_16x16x32_bf16(
            af[mt], bfr[nt], acc[mt][nt], 0, 0, 0);
    __syncthreads();
  }

  float b1v[4], w2v[4];
  #pragma unroll
  for (int nt = 0; nt < 4; ++nt) {
    b1v[nt] = b1[nt*16 + l16];
    w2v[nt] = W2[nt*16 + l16];
  }
  #pragma unroll
  for (int mt = 0; mt < 2; ++mt)
    #pragma unroll
    for (int rr = 0; rr < 4; ++rr) {
      float h = 0.f;
      #pragma unroll
      for (int nt = 0; nt < 4; ++nt)
        h += fmaxf(acc[mt][nt][rr] + b1v[nt], 0.f) * w2v[nt];
      #pragma unroll
      for (int o = 1; o < 16; o <<= 1) h += __shfl_xor(h, o);
      if (l16 == 0)
        e2out[m0 + wid*32 + mt*16 + quad*4 + rr] = h;
    }
}

// ---------------- fused row-softmax + weighted column-sum (bf16 E) --------
__global__ __launch_bounds__(256) void fused_sm_kernel(
    const ushort* __restrict__ E, const float* __restrict__ w,
    float* __restrict__ u_part)
{
  __shared__ float ul[4][1024];
  const int b = blockIdx.y;
  const int strip = blockIdx.x;       // 0..63
  const int t = threadIdx.x, wv = t >> 6, lane = t & 63;
  const ushort* Eb = E + (size_t)b*C_*C_;
  const float* wb = w + (size_t)b*C_;
  float acc[2][8] = {};               // i = c*512 + lane*8 + k
  #pragma unroll
  for (int rj = 0; rj < 4; ++rj) {
    const int j = strip*16 + wv*4 + rj;
    const ushort* row = Eb + (size_t)j*C_;
    float vv[2][8];
    float m = -1e30f;
    #pragma unroll
    for (int c = 0; c < 2; ++c) {
      ushortx8 h = *(const ushortx8*)&row[c*512 + lane*8];
      #pragma unroll
      for (int kk = 0; kk < 8; ++kk) {
        vv[c][kk] = bf2f(h[kk]);
        m = fmaxf(m, vv[c][kk]);
      }
    }
    m = wave_max(m);
    float e[2][8];
    float s = 0.f;
    #pragma unroll
    for (int c = 0; c < 2; ++c)
      #pragma unroll
      for (int kk = 0; kk < 8; ++kk) {
        e[c][kk] = expf(vv[c][kk] - m);
        s += e[c][kk];
      }
    s = wave_sum(s);
    const float sc = wb[j] / s;
    #pragma unroll
    for (int c = 0; c < 2; ++c)
      #pragma unroll
      for (int kk = 0; kk < 8; ++kk) acc[c][kk] += sc * e[c][kk];
  }
  #pragma unroll
  for (int c = 0; c < 2; ++c)
    #pragma unroll
    for (int k4 = 0; k4 < 2; ++k4) {
      float4 o;
      o.x = acc[c][k4*4+0]; o.y = acc[c][k4*4+1];
      o.z = acc[c][k4*4+2]; o.w = acc[c][k4*4+3];
      *(float4*)&ul[wv][c*512 + lane*8 + k4*4] = o;
    }
  __syncthreads();
  float4 r0 = *(float4*)&ul[0][t*4];
  float4 r1 = *(float4*)&ul[1][t*4];
  float4 r2 = *(float4*)&ul[2][t*4];
  float4 r3 = *(float4*)&ul[3][t*4];
  float4 o;
  o.x = r0.x+r1.x+r2.x+r3.x; o.y = r0.y+r1.y+r2.y+r3.y;
  o.z = r0.z+r1.z+r2.z+r3.z; o.w = r0.w+r1.w+r2.w+r3.w;
  *(float4*)&u_part[((size_t)strip*B_ + b)*C_ + t*4] = o;
}

// ---------------- pooling softmax ----------------
__global__ __launch_bounds__(256) void softmax_w_kernel(
    const float* __restrict__ e2in, float* __restrict__ w)
{
  __shared__ float redm[4];
  __shared__ float reds[4];
  const int b = blockIdx.x, t = threadIdx.x;
  const int lane = t & 63, wid = t >> 6;
  const float* row = e2in + (size_t)b*C_;
  float4 v = *(const float4*)&row[t*4];
  float m = fmaxf(fmaxf(v.x, v.y), fmaxf(v.z, v.w));
  m = wave_max(m);
  if (lane == 0) redm[wid] = m;
  __syncthreads();
  m = fmaxf(fmaxf(redm[0], redm[1]), fmaxf(redm[2], redm[3]));
  float e0 = expf(v.x - m), e1 = expf(v.y - m);
  float e2 = expf(v.z - m), e3 = expf(v.w - m);
  float s = e0 + e1 + e2 + e3;
  s = wave_sum(s);
  if (lane == 0) reds[wid] = s;
  __syncthreads();
  s = reds[0] + reds[1] + reds[2] + reds[3];
  const float inv = 1.0f / s;
  float4 o; o.x = e0*inv; o.y = e1*inv; o.z = e2*inv; o.w = e3*inv;
  *(float4*)&w[(size_t)b*C_ + t*4] = o;
}

// ---------------- final reduction: u-combine fused in, split over i -------
__global__ __launch_bounds__(256) void final_part_kernel(
    const ushort* __restrict__ X, const ushort* __restrict__ V,
    const float* __restrict__ u_part, const float* __restrict__ w,
    const float* __restrict__ gamma, float* __restrict__ fpart)
{
  const int b = blockIdx.x, s = blockIdx.y;    // i in [s*16, s*16+16)
  const int t = threadIdx.x;
  __shared__ float red[16][17];
  __shared__ float us[16];
  {
    const int ii = t & 15, g = t >> 4;         // g sums 4 strips
    float p = 0.f;
    #pragma unroll
    for (int q2 = 0; q2 < 4; ++q2) {
      const int sp = g*4 + q2;
      p += u_part[((size_t)sp*B_ + b)*C_ + s*16 + ii];
    }
    red[ii][g] = p;
  }
  __syncthreads();
  if (t < 16) {
    float s2 = 0.f;
    #pragma unroll
    for (int g = 0; g < 16; ++g) s2 += red[t][g];
    us[t] = s2;
  }
  __syncthreads();

  const int d0 = t * 4;
  const ushort* xb = X + (size_t)b*C_*D_;
  const ushort* vb = V + (size_t)b*C_*D_;
  const float* wb = w + (size_t)b*C_;
  float4 av = {0,0,0,0}, ax = {0,0,0,0};
  #pragma unroll
  for (int ii = 0; ii < 16; ++ii) {
    const int i = s*16 + ii;
    const float ui = us[ii], wi = wb[i];
    ushort4 vv = *(const ushort4*)&vb[(size_t)i*D_ + d0];
    ushort4 xv = *(const ushort4*)&xb[(size_t)i*D_ + d0];
    av.x += ui*bf2f(vv.x); av.y += ui*bf2f(vv.y);
    av.z += ui*bf2f(vv.z); av.w += ui*bf2f(vv.w);
    ax.x += wi*bf2f(xv.x); ax.y += wi*bf2f(xv.y);
    ax.z += wi*bf2f(xv.z); ax.w += wi*bf2f(xv.w);
  }
  const float g = gamma[0];
  float4 o;
  o.x = g*av.x + ax.x; o.y = g*av.y + ax.y;
  o.z = g*av.z + ax.z; o.w = g*av.w + ax.w;
  *(float4*)&fpart[((size_t)s*B_ + b)*D_ + d0] = o;
}

__global__ __launch_bounds__(256) void final_combine_kernel(
    const float* __restrict__ fpart, float* __restrict__ out)
{
  const int idx = blockIdx.x*256 + threadIdx.x;   // over B_*D_
  float s = 0.f;
  #pragma unroll 8
  for (int sp = 0; sp < 64; ++sp) s += fpart[(size_t)sp*B_*D_ + idx];
  out[idx] = s;
}

extern "C" void kernel_launch(void* const* d_in, const int* in_sizes, int n_in,
                              void* d_out, int out_size, void* d_ws, size_t ws_size,
                              hipStream_t stream) {
  (void)in_sizes; (void)n_in; (void)out_size; (void)ws_size;
  const float* x  = (const float*)d_in[0];
  const float* Wf = (const float*)d_in[1];
  const float* bf = (const float*)d_in[2];
  const float* Wg = (const float*)d_in[3];
  const float* bg = (const float*)d_in[4];
  const float* Wx = (const float*)d_in[5];
  const float* bx = (const float*)d_in[6];
  const float* W1 = (const float*)d_in[7];
  const float* b1 = (const float*)d_in[8];
  const float* W2 = (const float*)d_in[9];
  const float* gamma = (const float*)d_in[11];
  float* out = (float*)d_out;

  // workspace layout (~140 MB total)
  ushort* x_bf = (ushort*)d_ws;                  // 32 MB
  ushort* wt   = x_bf + (size_t)M_*D_;           // 6 MB (Wf^T|Wg^T|Wx^T contiguous)
  ushort* w1t  = wt + (size_t)3*D_*D_;           // 128 KB
  ushort* q_bf = w1t + (size_t)H_*D_;            // 32 MB
  ushort* k_bf = q_bf + (size_t)M_*D_;           // 32 MB
  ushort* v_bf = k_bf + (size_t)M_*D_;           // 32 MB
  ushort* E    = v_bf + (size_t)M_*D_;           // 32 MB (bf16, all batches)
  float*  e2b  = (float*)(E + (size_t)B_*C_*C_); // 64 KB
  float*  wbuf = e2b + M_;                       // 64 KB
  float*  u_part = wbuf + M_;                    // 4 MB
  float*  fpart  = (float*)E;                    // alias: E dead after fused_sm

  // prep: x->bf16 + weight transposes, one launch
  prep_kernel<<<dim3(16384+3072+64), 256, 0, stream>>>(
      x, Wf, Wg, Wx, W1, x_bf, wt, w1t);

  // merged q/k/v projection (bf16 MFMA, N=3072, BK=64, 3 blocks/CU)
  proj_kernel<<<dim3(24,128), 256, 0, stream>>>(x_bf, wt, bf, bg, bx,
                                                q_bf, k_bf, v_bf);

  // pooling weights (MFMA MLP + softmax)
  pool_mfma_kernel<<<dim3(M_/128), 256, 0, stream>>>(x_bf, w1t, b1, W2, e2b);
  softmax_w_kernel<<<dim3(B_), 256, 0, stream>>>(e2b, wbuf);

  // energy (64x128 tile, 4 blocks/CU, exact 2 rounds) + fused softmax/colsum
  energy_kernel<<<dim3(8,16,B_), 256, 0, stream>>>(k_bf, q_bf, E);
  fused_sm_kernel<<<dim3(64,B_), 256, 0, stream>>>(E, wbuf, u_part);

  // final: u-combine + split-i reduction into fpart, then combine
  final_part_kernel<<<dim3(B_,64), 256, 0, stream>>>(x_bf, v_bf, u_part, wbuf,
                                                     gamma, fpart);
  final_combine_kernel<<<dim3(M_/256), 256, 0, stream>>>(fpart, out);
}